// Round 8
// baseline (329.643 us; speedup 1.0000x reference)
//
#include <hip/hip_runtime.h>
#include <hip/hip_fp16.h>
#include <stdint.h>

#define OUT_F 4096
#define IN_F  4096
#define M_DIM 8192
#define K_DIM IN_F
#define N_DIM OUT_F
#define GROUPS (OUT_F * IN_F / 64)
#define NTRIP  (GROUPS * 8)
#define NPARAM (GROUPS * 2)

typedef __attribute__((ext_vector_type(4))) float f32x4;
typedef __attribute__((ext_vector_type(8))) short bf16x8;
typedef __attribute__((ext_vector_type(8))) unsigned short u16x8;

static __device__ __forceinline__ unsigned short f32_to_bf16(float f) {
    unsigned int u = __builtin_bit_cast(unsigned int, f);
    u += 0x7fffu + ((u >> 16) & 1u);
    return (unsigned short)(u >> 16);
}

// ---------------- params dtype detection (f16 vs f32 on device) ----------------
__global__ void flag_init(int* f) { f[0] = 0; }

__global__ __launch_bounds__(256) void detect_f16(const __half* __restrict__ p,
                                                  int* __restrict__ flag) {
    int big = 0;
    for (int i = blockIdx.x * 256 + threadIdx.x; i < NPARAM; i += 256 * 256) {
        float v = __half2float(p[i]);
        if (!(fabsf(v) < 1.0f)) big = 1;
    }
    if (big) atomicOr(flag, 1);
}

// ---------------- dequant: 3-bit packed -> bf16 W[N][K] row-major ----------------
__global__ __launch_bounds__(256) void dequant3(const int* __restrict__ pk,
                                                const void* __restrict__ params,
                                                const int* __restrict__ flag,
                                                unsigned short* __restrict__ W) {
    int t = blockIdx.x * 256 + threadIdx.x;
    int b0 = pk[3 * t + 0];
    int b1 = pk[3 * t + 1];
    int b2 = pk[3 * t + 2];
    int g = t >> 3;
    float lo, hi;
    if (flag[0] == 0) {
        const __half* p = (const __half*)params;
        lo = __half2float(p[2 * g + 0]);
        hi = __half2float(p[2 * g + 1]);
    } else {
        const float* p = (const float*)params;
        lo = p[2 * g + 0];
        hi = p[2 * g + 1];
    }
    float s = (hi - lo) * (1.0f / 7.0f);

    int q[8];
    q[0] = b0 & 7;
    q[1] = (b0 >> 3) & 7;
    q[2] = ((b0 >> 6) & 3) | ((b1 & 1) << 2);
    q[3] = (b1 >> 1) & 7;
    q[4] = (b1 >> 4) & 7;
    q[5] = ((b1 >> 7) & 1) | ((b2 & 3) << 1);
    q[6] = (b2 >> 2) & 7;
    q[7] = (b2 >> 5) & 7;

    u16x8 o;
#pragma unroll
    for (int j = 0; j < 8; j++) {
        float w = (float)q[j] * s + lo;
        o[j] = f32_to_bf16(w);
    }
    *(u16x8*)&W[8 * (size_t)t] = o;
}

// ---------------- x: f32 -> bf16 ----------------
__global__ __launch_bounds__(256) void cvt_x(const float* __restrict__ x,
                                             unsigned short* __restrict__ xb) {
    size_t t = (size_t)blockIdx.x * 256 + threadIdx.x;
    f32x4 a = *(const f32x4*)&x[8 * t];
    f32x4 b = *(const f32x4*)&x[8 * t + 4];
    u16x8 o;
#pragma unroll
    for (int j = 0; j < 4; j++) o[j] = f32_to_bf16(a[j]);
#pragma unroll
    for (int j = 0; j < 4; j++) o[4 + j] = f32_to_bf16(b[j]);
    *(u16x8*)&xb[8 * t] = o;
}

// ======== 256x128 GEMM, BK=32 windows, triple-buffer LDS, 2 blocks/CU ========
// 4 waves (2x2), wave tile 128x64: acc[8][4]=128 AGPR + Fa/Fb frag sets 96 VGPR
// fits the 256-reg/wave cap (2 waves/SIMD). LDS 72 KB (3 bufs x 24 KB) -> two
// INDEPENDENT blocks per CU: one block's MFMA overlaps the other's LDS phase.
// Window kb: {read F_next <- tile kb+1; stage tile kb+3 -> buf[kb%3];
//             MFMA(F_cur); lgkm(0); vmcnt(6); barrier}.
// vmcnt(6) at window END drains tile kb+2 (aged ~1.5 windows) in EVERY wave
// before the barrier -> reads at kb+1 are cross-wave safe. lgkm(0) protects
// this window's reads from next window's re-stage of the same buffer.
// Bank swizzle (64B rows): phys = (row ^ ((row>>2)&1))*64 + ((chunk^(row&3))<<4)
// -> 8 bank-groups x 2-way (free). Staging source pre-permuted (involution).

#define LGKM0 asm volatile("s_waitcnt lgkmcnt(0)" ::: "memory")
#define VMW(n) asm volatile("s_waitcnt vmcnt(" #n ")" ::: "memory")
#define BAR() asm volatile("s_barrier" ::: "memory")

#define GLO(gp, lp) __builtin_amdgcn_global_load_lds( \
    (const __attribute__((address_space(1))) unsigned int*)(gp), \
    (__attribute__((address_space(3))) unsigned int*)(lp), 16, 0, 0)

// read 8 A-frags + 4 B-frags (one K=32 tile) into set F
#define READ12(F, roff) do { \
  _Pragma("unroll") for (int m_ = 0; m_ < 8; ++m_) \
    F##A[m_] = *(const bf16x8*)(shb + (roff) + arow_b + m_ * 1024 + cbr); \
  _Pragma("unroll") for (int n_ = 0; n_ < 4; ++n_) \
    F##B[n_] = *(const bf16x8*)(shb + (roff) + 16384 + brow_b + n_ * 1024 + cbr); \
} while (0)

#define MFMA32(F) do { __builtin_amdgcn_s_setprio(1); \
  _Pragma("unroll") for (int m_ = 0; m_ < 8; ++m_) \
  _Pragma("unroll") for (int n_ = 0; n_ < 4; ++n_) \
    acc[m_][n_] = __builtin_amdgcn_mfma_f32_16x16x32_bf16(F##A[m_], F##B[n_], acc[m_][n_], 0, 0, 0); \
  __builtin_amdgcn_s_setprio(0); } while (0)

// stage one K=32 tile: A 256x32 (4 rounds) + B 128x32 (2 rounds)
#define STAGE(soff, kt) do { \
  _Pragma("unroll") for (int c_ = 0; c_ < 4; ++c_) \
    GLO(GAb + (size_t)(kt) * 64 + c_ * 524288 + vbase, shw + (soff) + c_ * 4096 + w4 * 1024); \
  _Pragma("unroll") for (int c_ = 0; c_ < 2; ++c_) \
    GLO(GBb + (size_t)(kt) * 64 + c_ * 524288 + vbase, shw + (soff) + 16384 + c_ * 4096 + w4 * 1024); \
} while (0)

__global__ __launch_bounds__(256, 2) void gemm_tb(const unsigned short* __restrict__ A,
                                                  const unsigned short* __restrict__ B,
                                                  const float* __restrict__ bias,
                                                  float* __restrict__ C) {
    __shared__ unsigned short sh[3 * 12288];     // 72 KiB: 3 bufs x (A 16K + B 8K)

    // bijective XCD swizzle: nwg = 1024, cpx = 128
    int bid = blockIdx.x;
    int swz = (bid & 7) * 128 + (bid >> 3);
    int bm = swz >> 5, bn = swz & 31;            // 32 x 32 tiles
    const int row0 = bm * 256, col0 = bn * 128;

    const int t = threadIdx.x;
    const int lane = t & 63;
    const int w4 = t >> 6;                       // wave 0..3
    const int wm = w4 >> 1, wn = w4 & 1;         // 2x2 waves, each 128x64

    // ---- staging source pre-permutation (lane-local, loop-invariant) ----
    // phys dest = base + lane*16 (linear). Inverse perm gives logical (row,chunk).
    const int b2s = (lane >> 4) & 1;                       // bit2 of (lane>>2)
    const int lrow = ((lane >> 2) ^ b2s);                  // logical row within 16
    const int lchk = (lane & 3) ^ (lrow & 3);              // logical chunk
    const int vbase = (w4 * 16 + lrow) * 8192 + lchk * 16; // byte offset in global

    // ---- fragment read addressing ----
    const int fr = lane & 15;
    const int kg = lane >> 4;
    const int b2f = (fr >> 2) & 1;
    const int cbr = ((kg ^ (fr & 3)) << 4);
    const int arow_b = (wm * 128 + (fr ^ b2f)) * 64;
    const int brow_b = (wn * 64 + (fr ^ b2f)) * 64;

    const char* GAb = (const char*)A + (size_t)row0 * 8192;
    const char* GBb = (const char*)B + (size_t)col0 * 8192;
    const char* shb = (const char*)sh;
    char* shw = (char*)sh;

    f32x4 acc[8][4] = {};
    bf16x8 FaA[8], FaB[4], FbA[8], FbB[4];

    // prologue: stage tiles 0,1,2 into bufs 0,1,2; publish t0,t1; prime Fa<-t0
    STAGE(0, 0); STAGE(24576, 1); STAGE(49152, 2);
    VMW(6);                    // t0,t1 complete; t2 in flight
    BAR();
    READ12(Fa, 0);
    LGKM0;
    BAR();                     // protect prime-read from window-0's stage(buf0)

    int r0 = 0, r1 = 24576, r2 = 49152;          // bufs (kb%3,(kb+1)%3,(kb+2)%3)

    for (int j = 0; j < 61; ++j) {
        const int kb = 2 * j;
        // window kb (even): cur Fa; read Fb <- tile kb+1; stage kb+3 -> buf[kb%3]
        READ12(Fb, r1);
        STAGE(r0, kb + 3);
        MFMA32(Fa);
        LGKM0; VMW(6); BAR();
        // window kb+1 (odd): cur Fb; read Fa <- tile kb+2; stage kb+4
        READ12(Fa, r2);
        STAGE(r1, kb + 4);
        MFMA32(Fb);
        LGKM0; VMW(6); BAR();
        int tmp = r0; r0 = r2; r2 = r1; r1 = tmp;   // advance by 2 windows
    }
    // windows 122..127 peeled (last stage at 124 -> tile 127)
    READ12(Fb, r1); STAGE(r0, 125); MFMA32(Fa); LGKM0; VMW(6); BAR();   // w122
    READ12(Fa, r2); STAGE(r1, 126); MFMA32(Fb); LGKM0; VMW(6); BAR();   // w123
    { int tmp = r0; r0 = r2; r2 = r1; r1 = tmp; }
    READ12(Fb, r1); STAGE(r0, 127); MFMA32(Fa); LGKM0; VMW(6); BAR();   // w124
    READ12(Fa, r2);                 MFMA32(Fb); LGKM0; VMW(0); BAR();   // w125
    READ12(Fb, r0);                 MFMA32(Fa); LGKM0; BAR();           // w126
    MFMA32(Fb);                                                         // w127

    // epilogue: C/D layout col=lane&15, row=(lane>>4)*4+j; fuse bias
    const int crow = kg * 4;
    const int ccol = fr;
#pragma unroll
    for (int mi = 0; mi < 8; ++mi) {
#pragma unroll
        for (int ni = 0; ni < 4; ++ni) {
            int col = col0 + wn * 64 + ni * 16 + ccol;
            float bv = bias[col];
#pragma unroll
            for (int jj = 0; jj < 4; ++jj) {
                int rw = row0 + wm * 128 + mi * 16 + crow + jj;
                C[(size_t)rw * N_DIM + col] = acc[mi][ni][jj] + bv;
            }
        }
    }
}

__global__ void ws_guard(float* out, float v) { out[0] = v; }

extern "C" void kernel_launch(void* const* d_in, const int* in_sizes, int n_in,
                              void* d_out, int out_size, void* d_ws, size_t ws_size,
                              hipStream_t stream) {
    const float* x      = (const float*)d_in[0];
    const int*   pk     = (const int*)d_in[1];
    const void*  params = (const void*)d_in[2];
    const float* bias   = (const float*)d_in[3];
    float* out = (float*)d_out;

    const size_t needW = (size_t)OUT_F * IN_F * 2;
    const size_t needX = (size_t)M_DIM * IN_F * 2;
    const size_t needF = 256;
    if (ws_size < needW + needX + needF) {
        ws_guard<<<1, 1, 0, stream>>>(out, 1.0e6f + (float)(ws_size >> 20));
        return;
    }
    unsigned short* W  = (unsigned short*)d_ws;
    unsigned short* Xb = (unsigned short*)((char*)d_ws + needW);
    int*            fl = (int*)((char*)d_ws + needW + needX);

    flag_init<<<1, 1, 0, stream>>>(fl);
    detect_f16<<<256, 256, 0, stream>>>((const __half*)params, fl);
    dequant3<<<NTRIP / 256, 256, 0, stream>>>(pk, params, fl, W);
    cvt_x<<<(int)(((size_t)M_DIM * IN_F / 8) / 256), 256, 0, stream>>>(x, Xb);
    gemm_tb<<<(M_DIM / 256) * (N_DIM / 128), 256, 0, stream>>>(Xb, W, bias, out);
}